// Round 3
// baseline (281.644 us; speedup 1.0000x reference)
//
#include <hip/hip_runtime.h>
#include <hip/hip_bf16.h>

#define WSZ 7
#define WD  49
#define NH  8
#define NWIN 64
#define HH  56
#define SS  3
#define TOK 3136
#define EMB 256

typedef __attribute__((ext_vector_type(8))) short bf16x8;
typedef __attribute__((ext_vector_type(4))) float f32x4;

// ---- LDS layout: 4 per-wave scratch regions, XOR-swizzled stride-64 rows ----
// per wave: QK[64][64] bf16 (Q cols 0-31, K cols 32-63) = 8192 B
//           VT[32][64] bf16                             = 4096 B   -> 12288 B/wave
// P[64][64] aliases QK (dead by softmax). Phase 2: sO[64][264] (33792 B) aliases all.
// Total 49152 B -> 3 blocks/CU (147456 <= 163840).
// SWZ keeps 16B alignment (XOR only bits>=3 of short index): b128 reads stay legal.
#define SWZ(row, col) ((col) ^ (((row) & 7) << 3))
#define PW_SH   6144      /* shorts per wave region */
#define VT_SH   4096      /* short offset of VT     */
#define LDS_TOTAL 49152
#define SO_STRIDE 264

// round-0-proven integer RNE f32->bf16 (no inline asm anywhere in this kernel:
// asm-written VGPRs feeding MFMA operands was the prime NaN suspect in r1/r2)
__device__ __forceinline__ unsigned short f2bf(float f) {
    union { float f; unsigned u; } v; v.f = f;
    return (unsigned short)((v.u + 0x7FFFu + ((v.u >> 16) & 1u)) >> 16);
}
__device__ __forceinline__ unsigned long long pack4(float a, float b, float c, float d) {
    return (unsigned long long)f2bf(a) | ((unsigned long long)f2bf(b) << 16)
         | ((unsigned long long)f2bf(c) << 32) | ((unsigned long long)f2bf(d) << 48);
}

// One block per (b, window): 4 waves. Phase 1: wave w -> heads 2w,2w+1.
// Phase 2: wave w -> output columns [64w, 64w+64).
__global__ __launch_bounds__(256, 3) void fused_kernel(
    const float* __restrict__ x, const float* __restrict__ qkv_w,
    const float* __restrict__ qkv_b, const unsigned short* __restrict__ pWt,
    const float* __restrict__ proj_b, const float* __restrict__ tbl,
    float* __restrict__ out)
{
    extern __shared__ char smem[];

    const int tid = threadIdx.x;
    const int w = blockIdx.x & 63, b = blockIdx.x >> 6;
    const int wi = w >> 3, wj = w & 7;
    const int cls = (((wi == 7) ? 1 : 0) << 1) | ((wj == 7) ? 1 : 0);
    const int wave = tid >> 6, lane = tid & 63;
    const int cl = lane & 15, quad = lane >> 4;

    // shifted token positions for this lane's 4 tokens (mt*16+cl); reused in epilogue
    int pos4[4];
    #pragma unroll
    for (int mt = 0; mt < 4; ++mt) {
        int tok = mt * 16 + cl;
        int ti = (tok * 37) >> 8;          // tok/7 for tok<70
        int tj = tok - ti * 7;
        int r = wi * WSZ + ti + SS; if (r >= HH) r -= HH;
        int c = wj * WSZ + tj + SS; if (c >= HH) c -= HH;
        pos4[mt] = r * HH + c;
    }

    // qkv weight fragments + biases straight from global (12 KB table, L2-hot).
    // Fragment element e = W[quad*8+e][j], j = outcol.  Identical for both heads.
    bf16x8 wQK[4]; float4 bQK[4];
    #pragma unroll
    for (int mt = 0; mt < 4; ++mt) {
        const float* wp = qkv_w + quad * 8 * 96 + (mt * 16 + cl);
        union { bf16x8 v; unsigned long long q[2]; } u;
        u.q[0] = pack4(wp[0],   wp[96],  wp[192], wp[288]);
        u.q[1] = pack4(wp[384], wp[480], wp[576], wp[672]);
        wQK[mt] = u.v;
        bQK[mt] = *(const float4*)(qkv_b + mt * 16 + quad * 4);
    }
    bf16x8 wV[2]; float bV[2];
    #pragma unroll
    for (int i = 0; i < 2; ++i) {
        const float* wp = qkv_w + quad * 8 * 96 + (64 + i * 16 + cl);
        union { bf16x8 v; unsigned long long q[2]; } u;
        u.q[0] = pack4(wp[0],   wp[96],  wp[192], wp[288]);
        u.q[1] = pack4(wp[384], wp[480], wp[576], wp[672]);
        wV[i] = u.v;
        bV[i] = qkv_b[64 + i * 16 + cl];
    }

    // x fragments for BOTH heads up front: head-1 load latency hides under head-0 compute
    bf16x8 xa2[2][4];
    #pragma unroll
    for (int mt = 0; mt < 4; ++mt) {
        const float* p = x + ((size_t)b * TOK + pos4[mt]) * EMB + quad * 8 + wave * 64;
        float4 v0 = *(const float4*)p;
        float4 v1 = *(const float4*)(p + 4);
        float4 v2 = *(const float4*)(p + 32);
        float4 v3 = *(const float4*)(p + 36);
        union { bf16x8 v; unsigned long long q[2]; } u0, u1;
        u0.q[0] = pack4(v0.x, v0.y, v0.z, v0.w);
        u0.q[1] = pack4(v1.x, v1.y, v1.z, v1.w);
        u1.q[0] = pack4(v2.x, v2.y, v2.z, v2.w);
        u1.q[1] = pack4(v3.x, v3.y, v3.z, v3.w);
        xa2[0][mt] = u0.v;
        xa2[1][mt] = u1.v;
    }

    unsigned short* sT  = (unsigned short*)smem + wave * PW_SH;  // QK tile / P alias
    unsigned short* sVT = sT + VT_SH;
    unsigned short* sP  = sT;

    const float qscale = 0.17677669529663687f;  // 1/sqrt(32)
    f32x4 otr[2][2][4];   // [head][mv][nt] O^T fragments

    #pragma unroll
    for (int hi = 0; hi < 2; ++hi) {
        const int h = wave * 2 + hi;
        // ---- Q,K transposed: D[m=outcol][n=token] -> packed b64 token-major stores ----
        #pragma unroll
        for (int mt = 0; mt < 4; ++mt) {          // outcol tiles (Q: 0,1; K: 2,3)
            #pragma unroll
            for (int nt = 0; nt < 4; ++nt) {      // token tiles
                f32x4 c = {bQK[mt].x, bQK[mt].y, bQK[mt].z, bQK[mt].w};
                c = __builtin_amdgcn_mfma_f32_16x16x32_bf16(wQK[mt], xa2[hi][nt], c, 0, 0, 0);
                int tok = nt * 16 + cl;
                if (mt < 2) {
                    int col0 = mt * 16 + quad * 4;
                    *(unsigned long long*)(&sT[tok * 64 + SWZ(tok, col0)]) =
                        pack4(c[0] * qscale, c[1] * qscale, c[2] * qscale, c[3] * qscale);
                } else {
                    int col0 = 32 + (mt - 2) * 16 + quad * 4;
                    *(unsigned long long*)(&sT[tok * 64 + SWZ(tok, col0)]) =
                        pack4(c[0], c[1], c[2], c[3]);
                }
            }
        }
        // ---- V original orientation: D[m=token][n=outcol] -> V^T b64 stores ----
        #pragma unroll
        for (int i = 0; i < 2; ++i) {
            #pragma unroll
            for (int mt = 0; mt < 4; ++mt) {
                f32x4 c = {bV[i], bV[i], bV[i], bV[i]};
                c = __builtin_amdgcn_mfma_f32_16x16x32_bf16(xa2[hi][mt], wV[i], c, 0, 0, 0);
                int hd = i * 16 + cl;
                *(unsigned long long*)(&sVT[hd * 64 + SWZ(hd, mt * 16 + quad * 4)]) =
                    pack4(c[0], c[1], c[2], c[3]);
            }
        }
        // ---- scores transposed: scT = K·Q^T + tbl; D[m=ktok][n=qtok] ----
        bf16x8 kb[4], qa[4];
        #pragma unroll
        for (int mt = 0; mt < 4; ++mt) {
            int rk = mt * 16 + cl;
            kb[mt] = *(const bf16x8*)(&sT[rk * 64 + SWZ(rk, 32 + quad * 8)]);
        }
        #pragma unroll
        for (int nt = 0; nt < 4; ++nt) {
            int rq = nt * 16 + cl;
            qa[nt] = *(const bf16x8*)(&sT[rq * 64 + SWZ(rq, quad * 8)]);
        }
        const float* tb = tbl + ((size_t)(cls * 8 + h) * 16) * 256 + lane * 4;
        f32x4 sc[4][4];
        #pragma unroll
        for (int mt = 0; mt < 4; ++mt)
            #pragma unroll
            for (int nt = 0; nt < 4; ++nt) {
                f32x4 c = *(const f32x4*)(tb + (mt * 4 + nt) * 256);
                sc[mt][nt] = __builtin_amdgcn_mfma_f32_16x16x32_bf16(kb[mt], qa[nt], c, 0, 0, 0);
            }
        // ---- softmax: per lane, qtok = nt*16+cl; keys in-lane (16) + cross-quad ----
        #pragma unroll
        for (int nt = 0; nt < 4; ++nt) {
            float e[4][4];
            float sm = 0.f;
            #pragma unroll
            for (int mt = 0; mt < 4; ++mt)
                #pragma unroll
                for (int r = 0; r < 4; ++r) {
                    float v = __expf(sc[mt][nt][r]);
                    e[mt][r] = v; sm += v;
                }
            sm += __shfl_xor(sm, 16);
            sm += __shfl_xor(sm, 32);
            float inv = 1.f / sm;
            int qt = nt * 16 + cl;
            #pragma unroll
            for (int mt = 0; mt < 4; ++mt)
                *(unsigned long long*)(&sP[qt * 64 + SWZ(qt, mt * 16 + quad * 4)]) =
                    pack4(e[mt][0] * inv, e[mt][1] * inv, e[mt][2] * inv, e[mt][3] * inv);
        }
        // ---- PV: O^T = V^T · P^T ----
        #pragma unroll
        for (int mv = 0; mv < 2; ++mv)
            #pragma unroll
            for (int nt = 0; nt < 4; ++nt) otr[hi][mv][nt] = (f32x4){0.f, 0.f, 0.f, 0.f};
        #pragma unroll
        for (int ks = 0; ks < 2; ++ks) {
            bf16x8 va[2], pb[4];
            #pragma unroll
            for (int mv = 0; mv < 2; ++mv) {
                int rv = mv * 16 + cl;
                va[mv] = *(const bf16x8*)(&sVT[rv * 64 + SWZ(rv, ks * 32 + quad * 8)]);
            }
            #pragma unroll
            for (int nt = 0; nt < 4; ++nt) {
                int rp = nt * 16 + cl;
                pb[nt] = *(const bf16x8*)(&sP[rp * 64 + SWZ(rp, ks * 32 + quad * 8)]);
            }
            #pragma unroll
            for (int mv = 0; mv < 2; ++mv)
                #pragma unroll
                for (int nt = 0; nt < 4; ++nt)
                    otr[hi][mv][nt] = __builtin_amdgcn_mfma_f32_16x16x32_bf16(va[mv], pb[nt], otr[hi][mv][nt], 0, 0, 0);
        }
    }

    // ---------- phase 2: projection ----------
    __syncthreads();
    unsigned short* sO = (unsigned short*)smem;
    #pragma unroll
    for (int hi = 0; hi < 2; ++hi) {
        const int h = wave * 2 + hi;
        #pragma unroll
        for (int mv = 0; mv < 2; ++mv)
            #pragma unroll
            for (int nt = 0; nt < 4; ++nt) {
                int qt = nt * 16 + cl;
                f32x4 o = otr[hi][mv][nt];
                *(unsigned long long*)(&sO[qt * SO_STRIDE + h * 32 + mv * 16 + quad * 4]) =
                    pack4(o[0], o[1], o[2], o[3]);
            }
    }
    __syncthreads();

    const int n0 = wave * 64;
    f32x4 acc[4][4];
    #pragma unroll
    for (int mt = 0; mt < 4; ++mt)
        #pragma unroll
        for (int tt = 0; tt < 4; ++tt) acc[mt][tt] = (f32x4){0.f, 0.f, 0.f, 0.f};
    #pragma unroll
    for (int ks = 0; ks < 8; ++ks) {
        bf16x8 wa[4], ob[4];
        #pragma unroll
        for (int mt = 0; mt < 4; ++mt)
            wa[mt] = *(const bf16x8*)(pWt + (size_t)(n0 + mt * 16 + cl) * 256 + ks * 32 + quad * 8);
        #pragma unroll
        for (int tt = 0; tt < 4; ++tt)
            ob[tt] = *(const bf16x8*)(&sO[(tt * 16 + cl) * SO_STRIDE + ks * 32 + quad * 8]);
        #pragma unroll
        for (int mt = 0; mt < 4; ++mt)
            #pragma unroll
            for (int tt = 0; tt < 4; ++tt)
                acc[mt][tt] = __builtin_amdgcn_mfma_f32_16x16x32_bf16(wa[mt], ob[tt], acc[mt][tt], 0, 0, 0);
    }
    #pragma unroll
    for (int mt = 0; mt < 4; ++mt) {
        float4 bq = *(const float4*)(proj_b + n0 + mt * 16 + quad * 4);
        #pragma unroll
        for (int tt = 0; tt < 4; ++tt) {
            int tok = tt * 16 + cl;
            if (tok < WD) {
                f32x4 v = acc[mt][tt];
                v[0] += bq.x; v[1] += bq.y; v[2] += bq.z; v[3] += bq.w;
                float* dst = out + ((size_t)b * TOK + pos4[tt]) * EMB + n0 + mt * 16 + quad * 4;
                *(f32x4*)dst = v;
            }
        }
    }
}

// ---- proj_w fp32 -> bf16 transpose: Wt[n][k] = bf16(W[k][n]) ----
__global__ __launch_bounds__(256) void cvt_kernel(
    const float* __restrict__ W, unsigned short* __restrict__ Wt)
{
    int i = blockIdx.x * 256 + threadIdx.x;
    int k = i >> 8, n = i & 255;
    Wt[n * 256 + k] = f2bf(W[i]);
}

// ---- bias+mask table in scores-MFMA C layout: tbl[cls][h][mt*4+nt][lane][r] ----
__global__ __launch_bounds__(256) void tbl_kernel(
    const float* __restrict__ rpb, float* __restrict__ tbl)
{
    int idx = blockIdx.x * 256 + threadIdx.x;      // 131072 total
    int r = idx & 3;
    int lane = (idx >> 2) & 63;
    int cl = lane & 15, quad = lane >> 4;
    int tile = (idx >> 8) & 15;
    int mt = tile >> 2, nt = tile & 3;
    int h = (idx >> 12) & 7;
    int cls = (idx >> 15) & 3;
    int ci = cls >> 1, cj = cls & 1;

    int ktok = mt * 16 + quad * 4 + r;
    int qtok = nt * 16 + cl;

    float v;
    if (ktok >= WD) v = -1e30f;                    // padded key -> exp = 0
    else if (qtok >= WD) v = 0.f;                  // padded query -> finite junk, discarded
    else {
        int qi = qtok / 7, qj = qtok - qi * 7;
        int ki = ktok / 7, kj = ktok - ki * 7;
        v = rpb[((qi - ki + 6) * 13 + (qj - kj + 6)) * NH + h];
        int qreg = (ci ? (qi < 4 ? 1 : 2) : 0) * 3 + (cj ? (qj < 4 ? 1 : 2) : 0);
        int kreg = (ci ? (ki < 4 ? 1 : 2) : 0) * 3 + (cj ? (kj < 4 ? 1 : 2) : 0);
        if (qreg != kreg) v -= 100.f;
    }
    tbl[idx] = v;
}

extern "C" void kernel_launch(void* const* d_in, const int* in_sizes, int n_in,
                              void* d_out, int out_size, void* d_ws, size_t ws_size,
                              hipStream_t stream) {
    const float* x      = (const float*)d_in[0];
    const float* qkv_w  = (const float*)d_in[1];
    const float* qkv_b  = (const float*)d_in[2];
    const float* proj_w = (const float*)d_in[3];
    const float* proj_b = (const float*)d_in[4];
    const float* rpb    = (const float*)d_in[5];
    float* out = (float*)d_out;

    const int B = in_sizes[0] / (TOK * EMB);

    unsigned short* pWt = (unsigned short*)d_ws;                      // 128 KB
    float* tbl = (float*)((char*)d_ws + 131072);                      // 512 KB

    (void)hipFuncSetAttribute(reinterpret_cast<const void*>(&fused_kernel),
                              hipFuncAttributeMaxDynamicSharedMemorySize, LDS_TOTAL);
    cvt_kernel<<<256, 256, 0, stream>>>(proj_w, pWt);
    tbl_kernel<<<512, 256, 0, stream>>>(rpb, tbl);
    fused_kernel<<<B * NWIN, 256, LDS_TOTAL, stream>>>(x, qkv_w, qkv_b, pWt, proj_b, tbl, out);
}

// Round 4
// 240.433 us; speedup vs baseline: 1.1714x; 1.1714x over previous
//
#include <hip/hip_runtime.h>
#include <hip/hip_bf16.h>

#define WSZ 7
#define WD  49
#define NH  8
#define NWIN 64
#define HH  56
#define SS  3
#define TOK 3136
#define EMB 256

typedef __attribute__((ext_vector_type(8))) short bf16x8;
typedef __attribute__((ext_vector_type(4))) float f32x4;

// ---- LDS layout: per-wave QK[64][64] (8 KB) + P[64][64] (8 KB) + VT[32][64] (4 KB)
// = 20480 B/wave -> 81920 B/block -> exactly 2 blocks/CU (163840 = 160 KiB).
// P is a DEDICATED buffer (no aliasing with QK): breaks the false anti-dependency
// that serialized head-1 QKV stores against head-0 PV reads.
// Phase 2: sO[64][264] (33792 B) aliases the whole region after __syncthreads.
// SWZ keeps 16B alignment (XOR only bits>=3 of short index): b128 reads stay legal.
#define SWZ(row, col) ((col) ^ (((row) & 7) << 3))
#define PW_SH   10240     /* shorts per wave region */
#define P_SH    4096      /* short offset of P      */
#define VT_SH   8192      /* short offset of VT     */
#define LDS_TOTAL 81920
#define SO_STRIDE 264

// round-0-proven integer RNE f32->bf16 (no inline asm anywhere in this kernel:
// the v_cvt_pk inline asm was isolated as the r1/r2 NaN source by the r2->r3 A/B)
__device__ __forceinline__ unsigned short f2bf(float f) {
    union { float f; unsigned u; } v; v.f = f;
    return (unsigned short)((v.u + 0x7FFFu + ((v.u >> 16) & 1u)) >> 16);
}
__device__ __forceinline__ unsigned long long pack4(float a, float b, float c, float d) {
    return (unsigned long long)f2bf(a) | ((unsigned long long)f2bf(b) << 16)
         | ((unsigned long long)f2bf(c) << 32) | ((unsigned long long)f2bf(d) << 48);
}

// One block per (b, window): 4 waves. Phase 1: wave w -> heads 2w,2w+1.
// Phase 2: wave w -> output columns [64w, 64w+64).
__global__ __launch_bounds__(256, 2) void fused_kernel(
    const float* __restrict__ x, const float* __restrict__ qkv_w,
    const float* __restrict__ qkv_b, const unsigned short* __restrict__ pWt,
    const float* __restrict__ proj_b, const float* __restrict__ tbl,
    float* __restrict__ out)
{
    extern __shared__ char smem[];

    const int tid = threadIdx.x;
    const int w = blockIdx.x & 63, b = blockIdx.x >> 6;
    const int wi = w >> 3, wj = w & 7;
    const int cls = (((wi == 7) ? 1 : 0) << 1) | ((wj == 7) ? 1 : 0);
    const int wave = tid >> 6, lane = tid & 63;
    const int cl = lane & 15, quad = lane >> 4;

    // shifted token positions for this lane's 4 tokens (mt*16+cl); reused in epilogue
    int pos4[4];
    #pragma unroll
    for (int mt = 0; mt < 4; ++mt) {
        int tok = mt * 16 + cl;
        int ti = (tok * 37) >> 8;          // tok/7 for tok<70
        int tj = tok - ti * 7;
        int r = wi * WSZ + ti + SS; if (r >= HH) r -= HH;
        int c = wj * WSZ + tj + SS; if (c >= HH) c -= HH;
        pos4[mt] = r * HH + c;
    }

    const float qscale = 0.17677669529663687f;  // 1/sqrt(32)
    f32x4 otr[2][2][4];   // [head][mv][nt] O^T fragments

    {   // ---------- phase 1 (scoped so restrict LDS pointers die before phase 2) ----------
        unsigned short* pwbase = (unsigned short*)smem + wave * PW_SH;
        unsigned short* __restrict__ sT  = pwbase;          // QK tile
        unsigned short* __restrict__ sP  = pwbase + P_SH;   // P (dedicated)
        unsigned short* __restrict__ sVT = pwbase + VT_SH;  // V^T

        // x fragments for BOTH heads up front: head-1 load latency hides under head-0
        bf16x8 xa2[2][4];
        #pragma unroll
        for (int mt = 0; mt < 4; ++mt) {
            const float* p = x + ((size_t)b * TOK + pos4[mt]) * EMB + quad * 8 + wave * 64;
            float4 v0 = *(const float4*)p;
            float4 v1 = *(const float4*)(p + 4);
            float4 v2 = *(const float4*)(p + 32);
            float4 v3 = *(const float4*)(p + 36);
            union { bf16x8 v; unsigned long long q[2]; } u0, u1;
            u0.q[0] = pack4(v0.x, v0.y, v0.z, v0.w);
            u0.q[1] = pack4(v1.x, v1.y, v1.z, v1.w);
            u1.q[0] = pack4(v2.x, v2.y, v2.z, v2.w);
            u1.q[1] = pack4(v3.x, v3.y, v3.z, v3.w);
            xa2[0][mt] = u0.v;
            xa2[1][mt] = u1.v;
        }

        // qkv weight fragments + biases straight from global (12 KB table, L2-hot).
        // Fragment element e = W[quad*8+e][j], j = outcol.  Identical for both heads.
        bf16x8 wQK[4]; float4 bQK[4];
        #pragma unroll
        for (int mt = 0; mt < 4; ++mt) {
            const float* wp = qkv_w + quad * 8 * 96 + (mt * 16 + cl);
            union { bf16x8 v; unsigned long long q[2]; } u;
            u.q[0] = pack4(wp[0],   wp[96],  wp[192], wp[288]);
            u.q[1] = pack4(wp[384], wp[480], wp[576], wp[672]);
            wQK[mt] = u.v;
            bQK[mt] = *(const float4*)(qkv_b + mt * 16 + quad * 4);
        }
        bf16x8 wV[2]; float bV[2];
        #pragma unroll
        for (int i = 0; i < 2; ++i) {
            const float* wp = qkv_w + quad * 8 * 96 + (64 + i * 16 + cl);
            union { bf16x8 v; unsigned long long q[2]; } u;
            u.q[0] = pack4(wp[0],   wp[96],  wp[192], wp[288]);
            u.q[1] = pack4(wp[384], wp[480], wp[576], wp[672]);
            wV[i] = u.v;
            bV[i] = qkv_b[64 + i * 16 + cl];
        }

        #pragma unroll
        for (int hi = 0; hi < 2; ++hi) {
            const int h = wave * 2 + hi;
            // ---- Q,K transposed: D[m=outcol][n=token] -> packed b64 token-major stores ----
            #pragma unroll
            for (int mt = 0; mt < 4; ++mt) {          // outcol tiles (Q: 0,1; K: 2,3)
                #pragma unroll
                for (int nt = 0; nt < 4; ++nt) {      // token tiles
                    f32x4 c = {bQK[mt].x, bQK[mt].y, bQK[mt].z, bQK[mt].w};
                    c = __builtin_amdgcn_mfma_f32_16x16x32_bf16(wQK[mt], xa2[hi][nt], c, 0, 0, 0);
                    int tok = nt * 16 + cl;
                    if (mt < 2) {
                        int col0 = mt * 16 + quad * 4;
                        *(unsigned long long*)(&sT[tok * 64 + SWZ(tok, col0)]) =
                            pack4(c[0] * qscale, c[1] * qscale, c[2] * qscale, c[3] * qscale);
                    } else {
                        int col0 = 32 + (mt - 2) * 16 + quad * 4;
                        *(unsigned long long*)(&sT[tok * 64 + SWZ(tok, col0)]) =
                            pack4(c[0], c[1], c[2], c[3]);
                    }
                }
            }
            // ---- V original orientation: D[m=token][n=outcol] -> V^T b64 stores ----
            #pragma unroll
            for (int i = 0; i < 2; ++i) {
                #pragma unroll
                for (int mt = 0; mt < 4; ++mt) {
                    f32x4 c = {bV[i], bV[i], bV[i], bV[i]};
                    c = __builtin_amdgcn_mfma_f32_16x16x32_bf16(xa2[hi][mt], wV[i], c, 0, 0, 0);
                    int hd = i * 16 + cl;
                    *(unsigned long long*)(&sVT[hd * 64 + SWZ(hd, mt * 16 + quad * 4)]) =
                        pack4(c[0], c[1], c[2], c[3]);
                }
            }
            // ---- scores transposed: scT = K·Q^T + tbl; D[m=ktok][n=qtok] ----
            bf16x8 kb[4], qa[4];
            #pragma unroll
            for (int mt = 0; mt < 4; ++mt) {
                int rk = mt * 16 + cl;
                kb[mt] = *(const bf16x8*)(&sT[rk * 64 + SWZ(rk, 32 + quad * 8)]);
            }
            #pragma unroll
            for (int nt = 0; nt < 4; ++nt) {
                int rq = nt * 16 + cl;
                qa[nt] = *(const bf16x8*)(&sT[rq * 64 + SWZ(rq, quad * 8)]);
            }
            const float* tb = tbl + ((size_t)(cls * 8 + h) * 16) * 256 + lane * 4;
            f32x4 sc[4][4];
            #pragma unroll
            for (int mt = 0; mt < 4; ++mt)
                #pragma unroll
                for (int nt = 0; nt < 4; ++nt) {
                    f32x4 c = *(const f32x4*)(tb + (mt * 4 + nt) * 256);
                    sc[mt][nt] = __builtin_amdgcn_mfma_f32_16x16x32_bf16(kb[mt], qa[nt], c, 0, 0, 0);
                }
            // ---- softmax: per lane, qtok = nt*16+cl; keys in-lane (16) + cross-quad ----
            #pragma unroll
            for (int nt = 0; nt < 4; ++nt) {
                float e[4][4];
                float sm = 0.f;
                #pragma unroll
                for (int mt = 0; mt < 4; ++mt)
                    #pragma unroll
                    for (int r = 0; r < 4; ++r) {
                        float v = __expf(sc[mt][nt][r]);
                        e[mt][r] = v; sm += v;
                    }
                sm += __shfl_xor(sm, 16);
                sm += __shfl_xor(sm, 32);
                float inv = 1.f / sm;
                int qt = nt * 16 + cl;
                #pragma unroll
                for (int mt = 0; mt < 4; ++mt)
                    *(unsigned long long*)(&sP[qt * 64 + SWZ(qt, mt * 16 + quad * 4)]) =
                        pack4(e[mt][0] * inv, e[mt][1] * inv, e[mt][2] * inv, e[mt][3] * inv);
            }
            // ---- PV: O^T = V^T · P^T ----
            #pragma unroll
            for (int mv = 0; mv < 2; ++mv)
                #pragma unroll
                for (int nt = 0; nt < 4; ++nt) otr[hi][mv][nt] = (f32x4){0.f, 0.f, 0.f, 0.f};
            #pragma unroll
            for (int ks = 0; ks < 2; ++ks) {
                bf16x8 va[2], pb[4];
                #pragma unroll
                for (int mv = 0; mv < 2; ++mv) {
                    int rv = mv * 16 + cl;
                    va[mv] = *(const bf16x8*)(&sVT[rv * 64 + SWZ(rv, ks * 32 + quad * 8)]);
                }
                #pragma unroll
                for (int nt = 0; nt < 4; ++nt) {
                    int rp = nt * 16 + cl;
                    pb[nt] = *(const bf16x8*)(&sP[rp * 64 + SWZ(rp, ks * 32 + quad * 8)]);
                }
                #pragma unroll
                for (int mv = 0; mv < 2; ++mv)
                    #pragma unroll
                    for (int nt = 0; nt < 4; ++nt)
                        otr[hi][mv][nt] = __builtin_amdgcn_mfma_f32_16x16x32_bf16(va[mv], pb[nt], otr[hi][mv][nt], 0, 0, 0);
            }
        }
    }   // ---------- end phase 1 scope ----------

    // ---------- phase 2: projection ----------
    __syncthreads();
    unsigned short* sO = (unsigned short*)smem;
    #pragma unroll
    for (int hi = 0; hi < 2; ++hi) {
        const int h = wave * 2 + hi;
        #pragma unroll
        for (int mv = 0; mv < 2; ++mv)
            #pragma unroll
            for (int nt = 0; nt < 4; ++nt) {
                int qt = nt * 16 + cl;
                f32x4 o = otr[hi][mv][nt];
                *(unsigned long long*)(&sO[qt * SO_STRIDE + h * 32 + mv * 16 + quad * 4]) =
                    pack4(o[0], o[1], o[2], o[3]);
            }
    }
    __syncthreads();

    const int n0 = wave * 64;
    f32x4 acc[4][4];
    #pragma unroll
    for (int mt = 0; mt < 4; ++mt)
        #pragma unroll
        for (int tt = 0; tt < 4; ++tt) acc[mt][tt] = (f32x4){0.f, 0.f, 0.f, 0.f};
    #pragma unroll
    for (int ks = 0; ks < 8; ++ks) {
        bf16x8 wa[4], ob[4];
        #pragma unroll
        for (int mt = 0; mt < 4; ++mt)   // pWt pre-arranged: 1 KB lane-contiguous per load
            wa[mt] = *(const bf16x8*)(pWt + (size_t)(((wave * 8 + ks) * 4 + mt) * 64 + lane) * 8);
        #pragma unroll
        for (int tt = 0; tt < 4; ++tt)
            ob[tt] = *(const bf16x8*)(&sO[(tt * 16 + cl) * SO_STRIDE + ks * 32 + quad * 8]);
        #pragma unroll
        for (int mt = 0; mt < 4; ++mt)
            #pragma unroll
            for (int tt = 0; tt < 4; ++tt)
                acc[mt][tt] = __builtin_amdgcn_mfma_f32_16x16x32_bf16(wa[mt], ob[tt], acc[mt][tt], 0, 0, 0);
    }
    #pragma unroll
    for (int mt = 0; mt < 4; ++mt) {
        float4 bq = *(const float4*)(proj_b + n0 + mt * 16 + quad * 4);
        #pragma unroll
        for (int tt = 0; tt < 4; ++tt) {
            int tok = tt * 16 + cl;
            if (tok < WD) {
                f32x4 v = acc[mt][tt];
                v[0] += bq.x; v[1] += bq.y; v[2] += bq.z; v[3] += bq.w;
                float* dst = out + ((size_t)b * TOK + pos4[tt]) * EMB + n0 + mt * 16 + quad * 4;
                *(f32x4*)dst = v;
            }
        }
    }
}

// ---- proj_w fp32 -> bf16, pre-arranged in phase-2 fragment order:
// Wt[(((wv*8+ks)*4+mt)*64 + quad*16+cl)*8 + e] = bf16(W[k][n]),
// with n = wv*64+mt*16+cl, k = ks*32+quad*8+e  (lane-contiguous 1 KB per fragment) ----
__global__ __launch_bounds__(256) void cvt_kernel(
    const float* __restrict__ W, unsigned short* __restrict__ Wt)
{
    int i = blockIdx.x * 256 + threadIdx.x;   // 65536 = 256*256, i = k*256 + n
    int k = i >> 8, n = i & 255;
    int wv = n >> 6, mt = (n >> 4) & 3, cl = n & 15;
    int ks = k >> 5, quad = (k >> 3) & 3, e = k & 7;
    Wt[(size_t)((((wv * 8 + ks) * 4 + mt) * 64) + quad * 16 + cl) * 8 + e] = f2bf(W[i]);
}

// ---- bias+mask table in scores-MFMA C layout: tbl[cls][h][mt*4+nt][lane][r] ----
__global__ __launch_bounds__(256) void tbl_kernel(
    const float* __restrict__ rpb, float* __restrict__ tbl)
{
    int idx = blockIdx.x * 256 + threadIdx.x;      // 131072 total
    int r = idx & 3;
    int lane = (idx >> 2) & 63;
    int cl = lane & 15, quad = lane >> 4;
    int tile = (idx >> 8) & 15;
    int mt = tile >> 2, nt = tile & 3;
    int h = (idx >> 12) & 7;
    int cls = (idx >> 15) & 3;
    int ci = cls >> 1, cj = cls & 1;

    int ktok = mt * 16 + quad * 4 + r;
    int qtok = nt * 16 + cl;

    float v;
    if (ktok >= WD) v = -1e30f;                    // padded key -> exp = 0
    else if (qtok >= WD) v = 0.f;                  // padded query -> finite junk, discarded
    else {
        int qi = qtok / 7, qj = qtok - qi * 7;
        int ki = ktok / 7, kj = ktok - ki * 7;
        v = rpb[((qi - ki + 6) * 13 + (qj - kj + 6)) * NH + h];
        int qreg = (ci ? (qi < 4 ? 1 : 2) : 0) * 3 + (cj ? (qj < 4 ? 1 : 2) : 0);
        int kreg = (ci ? (ki < 4 ? 1 : 2) : 0) * 3 + (cj ? (kj < 4 ? 1 : 2) : 0);
        if (qreg != kreg) v -= 100.f;
    }
    tbl[idx] = v;
}

extern "C" void kernel_launch(void* const* d_in, const int* in_sizes, int n_in,
                              void* d_out, int out_size, void* d_ws, size_t ws_size,
                              hipStream_t stream) {
    const float* x      = (const float*)d_in[0];
    const float* qkv_w  = (const float*)d_in[1];
    const float* qkv_b  = (const float*)d_in[2];
    const float* proj_w = (const float*)d_in[3];
    const float* proj_b = (const float*)d_in[4];
    const float* rpb    = (const float*)d_in[5];
    float* out = (float*)d_out;

    const int B = in_sizes[0] / (TOK * EMB);

    unsigned short* pWt = (unsigned short*)d_ws;                      // 128 KB
    float* tbl = (float*)((char*)d_ws + 131072);                      // 512 KB

    (void)hipFuncSetAttribute(reinterpret_cast<const void*>(&fused_kernel),
                              hipFuncAttributeMaxDynamicSharedMemorySize, LDS_TOTAL);
    cvt_kernel<<<256, 256, 0, stream>>>(proj_w, pWt);
    tbl_kernel<<<512, 256, 0, stream>>>(rpb, tbl);
    fused_kernel<<<B * NWIN, 256, LDS_TOTAL, stream>>>(x, qkv_w, qkv_b, pWt, proj_b, tbl, out);
}

// Round 6
// 237.695 us; speedup vs baseline: 1.1849x; 1.0115x over previous
//
#include <hip/hip_runtime.h>
#include <hip/hip_bf16.h>

#define WSZ 7
#define WD  49
#define NH  8
#define NWIN 64
#define HH  56
#define SS  3
#define TOK 3136
#define EMB 256

typedef __attribute__((ext_vector_type(8))) short bf16x8;
typedef __attribute__((ext_vector_type(4))) float f32x4;

// ---- LDS layout: per-wave QK[64][64] (8 KB) + P[64][64] (8 KB) + VT[32][64] (4 KB)
// = 20480 B/wave -> 81920 B/block -> exactly 2 blocks/CU (163840 = 160 KiB).
// P is a DEDICATED buffer (no aliasing with QK). Phase 2: sO[64][264] aliases all.
// SWZ keeps 16B alignment (XOR only bits>=3 of short index): b128 reads stay legal.
#define SWZ(row, col) ((col) ^ (((row) & 7) << 3))
#define PW_SH   10240     /* shorts per wave region */
#define P_SH    4096      /* short offset of P      */
#define VT_SH   8192      /* short offset of VT     */
#define LDS_TOTAL 81920
#define SO_STRIDE 264

// exact RNE f32->bf16 for prep kernels (cold path)
__device__ __forceinline__ unsigned short f2bf(float f) {
    union { float f; unsigned u; } v; v.f = f;
    return (unsigned short)((v.u + 0x7FFFu + ((v.u >> 16) & 1u)) >> 16);
}
// hot-path packing: round-half-up + v_perm_b32 byte select.
// dst = [bf16(a) | bf16(b)<<16]; 3 VALU ops per 2 elements (vs ~10 for RNE chain).
// Differs from RNE only on exact 0x8000 mantissa ties (<=1 ulp, statistically rare).
__device__ __forceinline__ unsigned cvt2p(float a, float b) {
    union { float f; unsigned u; } ua, ub;
    ua.f = a; ub.f = b;
    return __builtin_amdgcn_perm(ub.u + 0x8000u, ua.u + 0x8000u, 0x07060302u);
}
__device__ __forceinline__ unsigned long long pack4(float a, float b, float c, float d) {
    return (unsigned long long)cvt2p(a, b) | ((unsigned long long)cvt2p(c, d) << 32);
}

#define LOG2E 1.4426950408889634f

// One block per (b, window): 4 waves. Phase 1: wave w -> heads 2w,2w+1.
// Phase 2: wave w -> output columns [64w, 64w+64).
__global__ __launch_bounds__(256, 2) void fused_kernel(
    const float* __restrict__ x, const float* __restrict__ qkv_w,
    const float* __restrict__ qkv_b, const unsigned short* __restrict__ pWt,
    const float* __restrict__ proj_b, const float* __restrict__ tbl,
    float* __restrict__ out)
{
    extern __shared__ char smem[];

    const int tid = threadIdx.x;
    const int w = blockIdx.x & 63, b = blockIdx.x >> 6;
    const int wi = w >> 3, wj = w & 7;
    const int cls = (((wi == 7) ? 1 : 0) << 1) | ((wj == 7) ? 1 : 0);
    const int wave = tid >> 6, lane = tid & 63;
    const int cl = lane & 15, quad = lane >> 4;

    // shifted token positions for this lane's 4 tokens (mt*16+cl); reused in epilogue
    int pos4[4];
    #pragma unroll
    for (int mt = 0; mt < 4; ++mt) {
        int tok = mt * 16 + cl;
        int ti = (tok * 37) >> 8;          // tok/7 for tok<70
        int tj = tok - ti * 7;
        int r = wi * WSZ + ti + SS; if (r >= HH) r -= HH;
        int c = wj * WSZ + tj + SS; if (c >= HH) c -= HH;
        pos4[mt] = r * HH + c;
    }

    // Q scale folds 1/sqrt(32) AND log2(e): softmax then uses bare v_exp_f32 (exp2).
    const float qscale = 0.17677669529663687f * LOG2E;
    f32x4 otr[2][2][4];   // [head][mv][nt] O^T fragments

    {   // ---------- phase 1 (scoped so restrict LDS pointers die before phase 2) ----------
        unsigned short* pwbase = (unsigned short*)smem + wave * PW_SH;
        unsigned short* __restrict__ sT  = pwbase;          // QK tile
        unsigned short* __restrict__ sP  = pwbase + P_SH;   // P (dedicated)
        unsigned short* __restrict__ sVT = pwbase + VT_SH;  // V^T

        // x fragments for BOTH heads up front: head-1 load latency hides under head-0
        bf16x8 xa2[2][4];
        #pragma unroll
        for (int mt = 0; mt < 4; ++mt) {
            const float* p = x + ((size_t)b * TOK + pos4[mt]) * EMB + quad * 8 + wave * 64;
            float4 v0 = *(const float4*)p;
            float4 v1 = *(const float4*)(p + 4);
            float4 v2 = *(const float4*)(p + 32);
            float4 v3 = *(const float4*)(p + 36);
            union { bf16x8 v; unsigned long long q[2]; } u0, u1;
            u0.q[0] = pack4(v0.x, v0.y, v0.z, v0.w);
            u0.q[1] = pack4(v1.x, v1.y, v1.z, v1.w);
            u1.q[0] = pack4(v2.x, v2.y, v2.z, v2.w);
            u1.q[1] = pack4(v3.x, v3.y, v3.z, v3.w);
            xa2[0][mt] = u0.v;
            xa2[1][mt] = u1.v;
        }

        // qkv weight fragments + biases straight from global (12 KB table, L2-hot).
        // Fragment element e = W[quad*8+e][j], j = outcol.  Identical for both heads.
        bf16x8 wQK[4]; float4 bQK[4];
        #pragma unroll
        for (int mt = 0; mt < 4; ++mt) {
            const float* wp = qkv_w + quad * 8 * 96 + (mt * 16 + cl);
            union { bf16x8 v; unsigned long long q[2]; } u;
            u.q[0] = pack4(wp[0],   wp[96],  wp[192], wp[288]);
            u.q[1] = pack4(wp[384], wp[480], wp[576], wp[672]);
            wQK[mt] = u.v;
            bQK[mt] = *(const float4*)(qkv_b + mt * 16 + quad * 4);
        }
        bf16x8 wV[2]; float bV[2];
        #pragma unroll
        for (int i = 0; i < 2; ++i) {
            const float* wp = qkv_w + quad * 8 * 96 + (64 + i * 16 + cl);
            union { bf16x8 v; unsigned long long q[2]; } u;
            u.q[0] = pack4(wp[0],   wp[96],  wp[192], wp[288]);
            u.q[1] = pack4(wp[384], wp[480], wp[576], wp[672]);
            wV[i] = u.v;
            bV[i] = qkv_b[64 + i * 16 + cl];
        }

        #pragma unroll
        for (int hi = 0; hi < 2; ++hi) {
            const int h = wave * 2 + hi;
            // ---- Q,K transposed: D[m=outcol][n=token] -> packed b64 token-major stores ----
            #pragma unroll
            for (int mt = 0; mt < 4; ++mt) {          // outcol tiles (Q: 0,1; K: 2,3)
                #pragma unroll
                for (int nt = 0; nt < 4; ++nt) {      // token tiles
                    f32x4 c = {bQK[mt].x, bQK[mt].y, bQK[mt].z, bQK[mt].w};
                    c = __builtin_amdgcn_mfma_f32_16x16x32_bf16(wQK[mt], xa2[hi][nt], c, 0, 0, 0);
                    int tok = nt * 16 + cl;
                    if (mt < 2) {
                        int col0 = mt * 16 + quad * 4;
                        *(unsigned long long*)(&sT[tok * 64 + SWZ(tok, col0)]) =
                            pack4(c[0] * qscale, c[1] * qscale, c[2] * qscale, c[3] * qscale);
                    } else {
                        int col0 = 32 + (mt - 2) * 16 + quad * 4;
                        *(unsigned long long*)(&sT[tok * 64 + SWZ(tok, col0)]) =
                            pack4(c[0], c[1], c[2], c[3]);
                    }
                }
            }
            // ---- V original orientation: D[m=token][n=outcol] -> V^T b64 stores ----
            #pragma unroll
            for (int i = 0; i < 2; ++i) {
                #pragma unroll
                for (int mt = 0; mt < 4; ++mt) {
                    f32x4 c = {bV[i], bV[i], bV[i], bV[i]};
                    c = __builtin_amdgcn_mfma_f32_16x16x32_bf16(xa2[hi][mt], wV[i], c, 0, 0, 0);
                    int hd = i * 16 + cl;
                    *(unsigned long long*)(&sVT[hd * 64 + SWZ(hd, mt * 16 + quad * 4)]) =
                        pack4(c[0], c[1], c[2], c[3]);
                }
            }
            // ---- scores transposed: scT = K·Q^T + tbl; D[m=ktok][n=qtok] ----
            bf16x8 kb[4], qa[4];
            #pragma unroll
            for (int mt = 0; mt < 4; ++mt) {
                int rk = mt * 16 + cl;
                kb[mt] = *(const bf16x8*)(&sT[rk * 64 + SWZ(rk, 32 + quad * 8)]);
            }
            #pragma unroll
            for (int nt = 0; nt < 4; ++nt) {
                int rq = nt * 16 + cl;
                qa[nt] = *(const bf16x8*)(&sT[rq * 64 + SWZ(rq, quad * 8)]);
            }
            const float* tb = tbl + ((size_t)(cls * 8 + h) * 16) * 256 + lane * 4;
            f32x4 sc[4][4];
            #pragma unroll
            for (int mt = 0; mt < 4; ++mt)
                #pragma unroll
                for (int nt = 0; nt < 4; ++nt) {
                    f32x4 c = *(const f32x4*)(tb + (mt * 4 + nt) * 256);
                    sc[mt][nt] = __builtin_amdgcn_mfma_f32_16x16x32_bf16(kb[mt], qa[nt], c, 0, 0, 0);
                }
            // ---- softmax (exp2 domain): per lane, qtok = nt*16+cl ----
            #pragma unroll
            for (int nt = 0; nt < 4; ++nt) {
                float e[4][4];
                float sm = 0.f;
                #pragma unroll
                for (int mt = 0; mt < 4; ++mt)
                    #pragma unroll
                    for (int r = 0; r < 4; ++r) {
                        float v = __builtin_amdgcn_exp2f(sc[mt][nt][r]);
                        e[mt][r] = v; sm += v;
                    }
                sm += __shfl_xor(sm, 16);
                sm += __shfl_xor(sm, 32);
                float inv = 1.f / sm;
                int qt = nt * 16 + cl;
                #pragma unroll
                for (int mt = 0; mt < 4; ++mt)
                    *(unsigned long long*)(&sP[qt * 64 + SWZ(qt, mt * 16 + quad * 4)]) =
                        pack4(e[mt][0] * inv, e[mt][1] * inv, e[mt][2] * inv, e[mt][3] * inv);
            }
            // ---- PV: O^T = V^T · P^T ----
            #pragma unroll
            for (int mv = 0; mv < 2; ++mv)
                #pragma unroll
                for (int nt = 0; nt < 4; ++nt) otr[hi][mv][nt] = (f32x4){0.f, 0.f, 0.f, 0.f};
            #pragma unroll
            for (int ks = 0; ks < 2; ++ks) {
                bf16x8 va[2], pb[4];
                #pragma unroll
                for (int mv = 0; mv < 2; ++mv) {
                    int rv = mv * 16 + cl;
                    va[mv] = *(const bf16x8*)(&sVT[rv * 64 + SWZ(rv, ks * 32 + quad * 8)]);
                }
                #pragma unroll
                for (int nt = 0; nt < 4; ++nt) {
                    int rp = nt * 16 + cl;
                    pb[nt] = *(const bf16x8*)(&sP[rp * 64 + SWZ(rp, ks * 32 + quad * 8)]);
                }
                #pragma unroll
                for (int mv = 0; mv < 2; ++mv)
                    #pragma unroll
                    for (int nt = 0; nt < 4; ++nt)
                        otr[hi][mv][nt] = __builtin_amdgcn_mfma_f32_16x16x32_bf16(va[mv], pb[nt], otr[hi][mv][nt], 0, 0, 0);
            }
        }
    }   // ---------- end phase 1 scope ----------

    // ---- hoist phase-2 weight loads for ks=0..3: ~200cy L2 latency hides under
    //      the sO stores + barrier instead of serializing phase 2 (VGPR headroom:
    //      occupancy is LDS-bound at 2 blocks/CU, so up to 256 VGPR is free) ----
    bf16x8 wah[4][4];
    #pragma unroll
    for (int ksh = 0; ksh < 4; ++ksh)
        #pragma unroll
        for (int mt = 0; mt < 4; ++mt)
            wah[ksh][mt] = *(const bf16x8*)(pWt + (size_t)(((wave * 8 + ksh) * 4 + mt) * 64 + lane) * 8);

    // ---------- phase 2: projection ----------
    __syncthreads();
    unsigned short* sO = (unsigned short*)smem;
    #pragma unroll
    for (int hi = 0; hi < 2; ++hi) {
        const int h = wave * 2 + hi;
        #pragma unroll
        for (int mv = 0; mv < 2; ++mv)
            #pragma unroll
            for (int nt = 0; nt < 4; ++nt) {
                int qt = nt * 16 + cl;
                f32x4 o = otr[hi][mv][nt];
                *(unsigned long long*)(&sO[qt * SO_STRIDE + h * 32 + mv * 16 + quad * 4]) =
                    pack4(o[0], o[1], o[2], o[3]);
            }
    }
    __syncthreads();

    const int n0 = wave * 64;
    f32x4 acc[4][4];
    #pragma unroll
    for (int mt = 0; mt < 4; ++mt)
        #pragma unroll
        for (int tt = 0; tt < 4; ++tt) acc[mt][tt] = (f32x4){0.f, 0.f, 0.f, 0.f};
    #pragma unroll
    for (int ks = 0; ks < 8; ++ks) {
        bf16x8 wa[4], ob[4];
        #pragma unroll
        for (int mt = 0; mt < 4; ++mt)   // pWt pre-arranged: 1 KB lane-contiguous per load
            wa[mt] = (ks < 4) ? wah[ks][mt]
                   : *(const bf16x8*)(pWt + (size_t)(((wave * 8 + ks) * 4 + mt) * 64 + lane) * 8);
        #pragma unroll
        for (int tt = 0; tt < 4; ++tt)
            ob[tt] = *(const bf16x8*)(&sO[(tt * 16 + cl) * SO_STRIDE + ks * 32 + quad * 8]);
        #pragma unroll
        for (int mt = 0; mt < 4; ++mt)
            #pragma unroll
            for (int tt = 0; tt < 4; ++tt)
                acc[mt][tt] = __builtin_amdgcn_mfma_f32_16x16x32_bf16(wa[mt], ob[tt], acc[mt][tt], 0, 0, 0);
    }
    #pragma unroll
    for (int mt = 0; mt < 4; ++mt) {
        float4 bq = *(const float4*)(proj_b + n0 + mt * 16 + quad * 4);
        #pragma unroll
        for (int tt = 0; tt < 4; ++tt) {
            int tok = tt * 16 + cl;
            if (tok < WD) {
                f32x4 v = acc[mt][tt];
                v[0] += bq.x; v[1] += bq.y; v[2] += bq.z; v[3] += bq.w;
                float* dst = out + ((size_t)b * TOK + pos4[tt]) * EMB + n0 + mt * 16 + quad * 4;
                *(f32x4*)dst = v;
            }
        }
    }
}

// ---- proj_w fp32 -> bf16, pre-arranged in phase-2 fragment order:
// Wt[(((wv*8+ks)*4+mt)*64 + quad*16+cl)*8 + e] = bf16(W[k][n]),
// with n = wv*64+mt*16+cl, k = ks*32+quad*8+e  (lane-contiguous 1 KB per fragment) ----
__global__ __launch_bounds__(256) void cvt_kernel(
    const float* __restrict__ W, unsigned short* __restrict__ Wt)
{
    int i = blockIdx.x * 256 + threadIdx.x;   // 65536 = 256*256, i = k*256 + n
    int k = i >> 8, n = i & 255;
    int wv = n >> 6, mt = (n >> 4) & 3, cl = n & 15;
    int ks = k >> 5, quad = (k >> 3) & 3, e = k & 7;
    Wt[(size_t)((((wv * 8 + ks) * 4 + mt) * 64) + quad * 16 + cl) * 8 + e] = f2bf(W[i]);
}

// ---- bias+mask table in scores-MFMA C layout, PRE-SCALED by log2(e) so the
// fused softmax uses bare v_exp_f32 (exp2): tbl[cls][h][mt*4+nt][lane][r] ----
__global__ __launch_bounds__(256) void tbl_kernel(
    const float* __restrict__ rpb, float* __restrict__ tbl)
{
    int idx = blockIdx.x * 256 + threadIdx.x;      // 131072 total
    int r = idx & 3;
    int lane = (idx >> 2) & 63;
    int cl = lane & 15, quad = lane >> 4;
    int tile = (idx >> 8) & 15;
    int mt = tile >> 2, nt = tile & 3;
    int h = (idx >> 12) & 7;
    int cls = (idx >> 15) & 3;
    int ci = cls >> 1, cj = cls & 1;

    int ktok = mt * 16 + quad * 4 + r;
    int qtok = nt * 16 + cl;

    float v;
    if (ktok >= WD) v = -1e30f;                    // padded key -> exp = 0
    else if (qtok >= WD) v = 0.f;                  // padded query -> finite junk, discarded
    else {
        int qi = qtok / 7, qj = qtok - qi * 7;
        int ki = ktok / 7, kj = ktok - ki * 7;
        v = rpb[((qi - ki + 6) * 13 + (qj - kj + 6)) * NH + h];
        int qreg = (ci ? (qi < 4 ? 1 : 2) : 0) * 3 + (cj ? (qj < 4 ? 1 : 2) : 0);
        int kreg = (ci ? (ki < 4 ? 1 : 2) : 0) * 3 + (cj ? (kj < 4 ? 1 : 2) : 0);
        if (qreg != kreg) v -= 100.f;
    }
    tbl[idx] = v * 1.4426950408889634f;            // fold log2(e)
}

extern "C" void kernel_launch(void* const* d_in, const int* in_sizes, int n_in,
                              void* d_out, int out_size, void* d_ws, size_t ws_size,
                              hipStream_t stream) {
    const float* x      = (const float*)d_in[0];
    const float* qkv_w  = (const float*)d_in[1];
    const float* qkv_b  = (const float*)d_in[2];
    const float* proj_w = (const float*)d_in[3];
    const float* proj_b = (const float*)d_in[4];
    const float* rpb    = (const float*)d_in[5];
    float* out = (float*)d_out;

    const int B = in_sizes[0] / (TOK * EMB);

    unsigned short* pWt = (unsigned short*)d_ws;                      // 128 KB
    float* tbl = (float*)((char*)d_ws + 131072);                      // 512 KB

    (void)hipFuncSetAttribute(reinterpret_cast<const void*>(&fused_kernel),
                              hipFuncAttributeMaxDynamicSharedMemorySize, LDS_TOTAL);
    cvt_kernel<<<256, 256, 0, stream>>>(proj_w, pWt);
    tbl_kernel<<<512, 256, 0, stream>>>(rpb, tbl);
    fused_kernel<<<B * NWIN, 256, LDS_TOTAL, stream>>>(x, qkv_w, qkv_b, pWt, proj_b, tbl, out);
}